// Round 1
// 1123.854 us; speedup vs baseline: 1.0049x; 1.0049x over previous
//
#include <hip/hip_runtime.h>

// loss = -sum_i log(predictions[i, targets[i]]), B=262144, V=1024
// predictions: float32 [B,V]; targets: int32 [B] (harness delivers ints as int32)
// output: single float32 scalar.
//
// Structure: one thread per 4 rows. Targets loaded as int4 (16 B/lane,
// coalesced); the 4 dependent gathers are mutually independent -> ILP 4,
// so each wave issues 4 vmem gather instructions before waiting once.
// 65536 threads = 256 blocks x 256 threads (1024 waves, 4 waves/CU).
// Math kept identical to previous kernel (per-element __logf, fp32 sums).

#define B_ROWS 262144
#define V_COLS 1024

__global__ __launch_bounds__(256) void nll_gather_reduce4(
    const float* __restrict__ pred,
    const int*   __restrict__ tgt,
    float* __restrict__ out)
{
    int tid = blockIdx.x * blockDim.x + threadIdx.x;   // 0 .. 65535

    // 4 consecutive rows per thread; int4 target load is fully coalesced.
    int4 t = reinterpret_cast<const int4*>(tgt)[tid];

    size_t row0 = (size_t)tid * 4 * V_COLS;
    // 4 independent gathers (each hits its own 64B line in its own 4KB row)
    float p0 = pred[row0               + t.x];
    float p1 = pred[row0 +     V_COLS  + t.y];
    float p2 = pred[row0 + 2 * V_COLS  + t.z];
    float p3 = pred[row0 + 3 * V_COLS  + t.w];

    float local = (__logf(p0) + __logf(p1)) + (__logf(p2) + __logf(p3));

    // wave-64 butterfly reduction
    for (int off = 32; off > 0; off >>= 1)
        local += __shfl_down(local, off, 64);

    // cross-wave via LDS (256 threads = 4 waves)
    __shared__ float wsum[4];
    int lane = threadIdx.x & 63;
    int wave = threadIdx.x >> 6;
    if (lane == 0) wsum[wave] = local;
    __syncthreads();

    if (threadIdx.x == 0) {
        float s = (wsum[0] + wsum[1]) + (wsum[2] + wsum[3]);
        atomicAdd(out, -s);
    }
}

extern "C" void kernel_launch(void* const* d_in, const int* in_sizes, int n_in,
                              void* d_out, int out_size, void* d_ws, size_t ws_size,
                              hipStream_t stream) {
    const float* pred = (const float*)d_in[0];
    const int*   tgt  = (const int*)d_in[1];
    float* out = (float*)d_out;

    // d_out is re-poisoned to 0xAA before every timed launch — zero it here.
    hipMemsetAsync(out, 0, sizeof(float), stream);

    // 65536 threads, 4 rows each = 262144 rows.
    nll_gather_reduce4<<<256, 256, 0, stream>>>(pred, tgt, out);
}